// Round 12
// baseline (226.167 us; speedup 1.0000x reference)
//
#include <hip/hip_runtime.h>
#include <hip/hip_bf16.h>

// Chamfer distance: B=4, S=4, N=M=4096, D=3, fp32 in/out.
// out[s*B + b] = mean_n min_m d2(n,m) + mean_m min_n d2(n,m)
//
// R12: global-streamed MFMA (R10 layout) with latency hidden by TLP, not ILP.
// R10/R11 lesson: compiler defeats manual register prefetch (VGPR stayed 52;
// loads sunk to uses; ~950cyc/iter exposed L2 latency at 2-4 waves/SIMD).
// Fix: 2048 blocks x 256 thr = 8 blocks/CU -> ~6 waves/SIMD; a wave's ~70cyc
// iteration window stretches to >400cyc wall between iterations of OTHER
// waves -> L2 latency covered by wave interleave alone.
//  - block = (row-tile-pair rtp, pair, dir); 4 waves = 4 col-quarters.
//  - wave: 2 row-tiles x 32 col-tiles; B-frag = contiguous lane-permuted 1KB
//    block (fully coalesced global read, no LDS, no barriers in hot loop).
//  - col-quarter partials merged via 1KB LDS (R11's verified epilogue).
//  - XCD swizzle prob = blk&31: each XCD's L2 holds 4 problems (~1MB).
// Per-CU budget: L2 1MB @56B/cyc = 7.6us (binding), VALU ~3us, MFMA ~1.3us.
//
// Precision: fp32 -> bf16 hi+lo split; K=16 slots carry all hi/lo cross
// products AND folded norm terms (-|p|^2/2):
//   A[k] = [xh,xl,xh,xl, yh,yl,yh,yl, zh,zl,zh,zl, 1,1, nh,nl]
//   B[k] = [xh,xh,xl,xl, yh,yh,yl,yl, zh,zh,zl,zl, nh,nl, 1,1]
// dot = a.b - |a|^2/2 - |b|^2/2 = -d2/2; min d2 = max(-2*maxG, 0);
// absmax 0.0 vs harness in R8-R11.
// C/D layout (m74/m101): col=lane&31, row=(reg&3)+8*(reg>>2)+4*(lane>>5).

constexpr int BB = 4, NPTS = 4096, PAIRS = 16;
constexpr size_t ARR_ELEMS = (size_t)PAIRS * NPTS * 16;   // bf16 elems per packed array
// ws layout (bf16): [outA][tgtB][tgtA][outB], 2 MB each
constexpr size_t WS_NEED = 4 * ARR_ELEMS * 2 + 8192;

typedef __bf16 bf16x8 __attribute__((ext_vector_type(8)));
typedef float f32x16 __attribute__((ext_vector_type(16)));

// ---- pack: each point -> A-pattern row and B-pattern row ----
__global__ void pack2_kernel(const float* __restrict__ outp,
                             const float* __restrict__ tgtp,
                             __bf16* __restrict__ ws) {
  const int idx = blockIdx.x * 256 + threadIdx.x;   // 0..131071
  const int src = idx >> 16;                         // 0 = out_pts, 1 = tgt_pts
  const int pn  = idx & 65535;                       // pair*4096 + n
  const float* p = (src ? tgtp : outp) + (size_t)pn * 3;
  const float x = p[0], y = p[1], z = p[2];
  const float n2 = -0.5f * (x * x + y * y + z * z);
  const __bf16 xh = (__bf16)x, yh = (__bf16)y, zh = (__bf16)z, nh = (__bf16)n2;
  const __bf16 xl = (__bf16)(x - (float)xh);
  const __bf16 yl = (__bf16)(y - (float)yh);
  const __bf16 zl = (__bf16)(z - (float)zh);
  const __bf16 nl = (__bf16)(n2 - (float)nh);
  const __bf16 one = (__bf16)1.0f;

  union { __bf16 h[16]; uint4 q[2]; } u;
  // A pattern
  u.h[0]=xh; u.h[1]=xl; u.h[2]=xh; u.h[3]=xl;
  u.h[4]=yh; u.h[5]=yl; u.h[6]=yh; u.h[7]=yl;
  u.h[8]=zh; u.h[9]=zl; u.h[10]=zh; u.h[11]=zl;
  u.h[12]=one; u.h[13]=one; u.h[14]=nh; u.h[15]=nl;
  __bf16* aDst = ws + (src ? 2 : 0) * ARR_ELEMS + (size_t)pn * 16;
  ((uint4*)aDst)[0] = u.q[0]; ((uint4*)aDst)[1] = u.q[1];
  // B pattern
  u.h[0]=xh; u.h[1]=xh; u.h[2]=xl; u.h[3]=xl;
  u.h[4]=yh; u.h[5]=yh; u.h[6]=yl; u.h[7]=yl;
  u.h[8]=zh; u.h[9]=zh; u.h[10]=zl; u.h[11]=zl;
  u.h[12]=nh; u.h[13]=nl; u.h[14]=one; u.h[15]=one;
  __bf16* bDst = ws + (src ? 1 : 3) * ARR_ELEMS + (size_t)pn * 16;
  ((uint4*)bDst)[0] = u.q[0]; ((uint4*)bDst)[1] = u.q[1];
}

// ---- main: 2048 blocks x 256 thr. blk -> prob = blk&31 (XCD-resident),
// rtp = blk>>5 (0..63: rows rtp*64 .. +64 = 2 row-tiles).
// Wave w = col-quarter cq: col-tiles cq*32 .. +32.
__global__ __launch_bounds__(256, 6)
void chamfer_mfma5_kernel(const __bf16* __restrict__ ws,
                          float* __restrict__ out) {
  const int t = threadIdx.x, l = t & 63, w = t >> 6;
  const int c32 = l & 31, h = l >> 5;
  const int blk = blockIdx.x;
  const int prob = blk & 31;          // same-XCD blocks share 4 problems
  const int rtp  = blk >> 5;          // 0..63
  const int pair = prob & 15;
  const int dir  = prob >> 4;
  const int cq   = w;                 // col-quarter 0..3

  const __bf16* aArr = ws + (dir ? 2 : 0) * ARR_ELEMS;  // dir0: queries, dir1: refs
  const __bf16* bArr = ws + (dir ? 3 : 1) * ARR_ELEMS;  // dir0: refs, dir1: queries

  // Two persistent A fragments: rows rtp*64 (+32).
  const size_t arow = (size_t)pair * NPTS + rtp * 64 + c32;
  const bf16x8 af0 = *(const bf16x8*)(aArr + (arow)      * 16 + (size_t)h * 8);
  const bf16x8 af1 = *(const bf16x8*)(aArr + (arow + 32) * 16 + (size_t)h * 8);

  f32x16 zacc;
  #pragma unroll
  for (int i = 0; i < 16; ++i) zacc[i] = 0.0f;
  float rowM0[16], rowM1[16];
  #pragma unroll
  for (int i = 0; i < 16; ++i) { rowM0[i] = -3.0e38f; rowM1[i] = -3.0e38f; }

  // B-frag stream: tile ct of this wave's quarter at bbase + ct*512 elems;
  // per tile per wave one contiguous lane-permuted 1KB block (coalesced).
  const __bf16* bbase =
      bArr + ((size_t)pair * NPTS + cq * 1024 + c32) * 16 + (size_t)h * 8;

  #pragma unroll 4
  for (int it = 0; it < 16; ++it) {
    const bf16x8 b0 = *(const bf16x8*)(bbase + (size_t)(2 * it) * 512);
    const bf16x8 b1 = *(const bf16x8*)(bbase + (size_t)(2 * it + 1) * 512);
    const f32x16 a00 = __builtin_amdgcn_mfma_f32_32x32x16_bf16(af0, b0, zacc, 0, 0, 0);
    const f32x16 a01 = __builtin_amdgcn_mfma_f32_32x32x16_bf16(af0, b1, zacc, 0, 0, 0);
    const f32x16 a10 = __builtin_amdgcn_mfma_f32_32x32x16_bf16(af1, b0, zacc, 0, 0, 0);
    const f32x16 a11 = __builtin_amdgcn_mfma_f32_32x32x16_bf16(af1, b1, zacc, 0, 0, 0);
    #pragma unroll
    for (int i = 0; i < 16; ++i) {
      rowM0[i] = fmaxf(fmaxf(rowM0[i], a00[i]), a01[i]);   // v_max3_f32
      rowM1[i] = fmaxf(fmaxf(rowM1[i], a10[i]), a11[i]);   // v_max3_f32
    }
  }

  // Cross-lane max over the 32 cols resident in c32 (once per wave).
  #pragma unroll
  for (int m = 1; m < 32; m <<= 1) {
    #pragma unroll
    for (int i = 0; i < 16; ++i) {
      rowM0[i] = fmaxf(rowM0[i], __shfl_xor(rowM0[i], m, 64));
      rowM1[i] = fmaxf(rowM1[i], __shfl_xor(rowM1[i], m, 64));
    }
  }

  // Merge col-quarters: sMax[wave][tile][h][reg], written by lanes c32==0.
  __shared__ float sMax[4 * 2 * 2 * 16];   // 1 KB
  if (c32 == 0) {
    #pragma unroll
    for (int i = 0; i < 16; ++i) {
      sMax[((w * 2 + 0) * 2 + h) * 16 + i] = rowM0[i];
      sMax[((w * 2 + 1) * 2 + h) * 16 + i] = rowM1[i];
    }
  }
  __syncthreads();

  // Wave 0 finalizes the 64 rows of this row-tile-pair.
  if (t < 64) {
    const int tile = t >> 5, tr = t & 31;
    const int hh = (tr >> 2) & 1, reg = (tr & 3) + 4 * (tr >> 3);
    float g = -3.0e38f;
    #pragma unroll
    for (int ww = 0; ww < 4; ++ww)
      g = fmaxf(g, sMax[((ww * 2 + tile) * 2 + hh) * 16 + reg]);
    float d = fmaxf(-2.0f * g, 0.0f);   // min squared distance for row t
    #pragma unroll
    for (int off = 1; off < 64; off <<= 1) d += __shfl_xor(d, off, 64);
    if (t == 0) {
      const int bb = pair >> 2, sx = pair & 3;      // pair = b*S + s
      atomicAdd(&out[sx * BB + bb], d * (1.0f / NPTS));
    }
  }
}

// ---- R7 fallback (fp32 VALU, pk_fma) if ws is too small ----
typedef float v2f __attribute__((ext_vector_type(2)));
#define PK_FMA_ZW(g, q, rzw)                                              \
  asm("v_pk_fma_f32 %0, %1, %2, %2 op_sel:[0,0,1] op_sel_hi:[1,0,1]"      \
      : "=v"(g) : "v"(q), "v"(rzw))
#define PK_FMA_Y(g, q, rxy)                                               \
  asm("v_pk_fma_f32 %0, %1, %2, %0 op_sel:[0,1,0] op_sel_hi:[1,1,1]"      \
      : "+v"(g) : "v"(q), "v"(rxy))
#define PK_FMA_X(g, q, rxy)                                               \
  asm("v_pk_fma_f32 %0, %1, %2, %0 op_sel:[0,0,0] op_sel_hi:[1,0,1]"      \
      : "+v"(g) : "v"(q), "v"(rxy))

__global__ __launch_bounds__(1024, 4)
void chamfer_pk3_kernel(const float* __restrict__ out_pts,
                        const float* __restrict__ tgt_pts,
                        float* __restrict__ out) {
  const int t = threadIdx.x, l = t & 63, wid = t >> 6;
  const int qtile = blockIdx.x, pair = blockIdx.y, dir = blockIdx.z;
  const float* qbase = (dir == 0 ? out_pts : tgt_pts) + (size_t)pair * NPTS * 3;
  const float* rbase = (dir == 0 ? tgt_pts : out_pts) + (size_t)pair * NPTS * 3;
  __shared__ float4 sref[NPTS];
  #pragma unroll
  for (int k = 0; k < 4; ++k) {
    const int i = t + k * 1024;
    const float rx = rbase[3*i], ry = rbase[3*i+1], rz = rbase[3*i+2];
    sref[i] = make_float4(rx, ry, rz, -0.5f * (rx*rx + ry*ry + rz*rz));
  }
  v2f qx[4], qy[4], qz[4];
  #pragma unroll
  for (int p = 0; p < 4; ++p) {
    const int q0 = qtile * 512 + (2*p)*64 + l, q1 = q0 + 64;
    qx[p] = v2f{qbase[3*q0],   qbase[3*q1]};
    qy[p] = v2f{qbase[3*q0+1], qbase[3*q1+1]};
    qz[p] = v2f{qbase[3*q0+2], qbase[3*q1+2]};
  }
  float acc[8];
  #pragma unroll
  for (int j = 0; j < 8; ++j) acc[j] = -3.0e38f;
  __syncthreads();
  const int base = wid * 256;
  #pragma unroll 2
  for (int r = 0; r < 256; r += 2) {
    const float4 rf0 = sref[base + r], rf1 = sref[base + r + 1];
    v2f rxy0{rf0.x, rf0.y}, rzw0{rf0.z, rf0.w};
    v2f rxy1{rf1.x, rf1.y}, rzw1{rf1.z, rf1.w};
    #pragma unroll
    for (int p = 0; p < 4; ++p) {
      v2f g0, g1;
      PK_FMA_ZW(g0, qz[p], rzw0); PK_FMA_Y(g0, qy[p], rxy0); PK_FMA_X(g0, qx[p], rxy0);
      PK_FMA_ZW(g1, qz[p], rzw1); PK_FMA_Y(g1, qy[p], rxy1); PK_FMA_X(g1, qx[p], rxy1);
      acc[2*p]   = fmaxf(fmaxf(acc[2*p],   g0.x), g1.x);
      acc[2*p+1] = fmaxf(fmaxf(acc[2*p+1], g0.y), g1.y);
    }
  }
  __syncthreads();
  float* Sf = reinterpret_cast<float*>(sref);
  #pragma unroll
  for (int j = 0; j < 8; ++j) Sf[wid * 512 + j * 64 + l] = acc[j];
  __syncthreads();
  if (t < 512) {
    float g = Sf[t];
    #pragma unroll
    for (int w2 = 1; w2 < 16; ++w2) g = fmaxf(g, Sf[w2 * 512 + t]);
    const int j = t >> 6, p = j >> 1, hh = j & 1;
    const float x2 = qx[p][hh]*qx[p][hh] + qy[p][hh]*qy[p][hh] + qz[p][hh]*qz[p][hh];
    float d = fmaxf(fmaf(-2.0f, g, x2), 0.0f);
    #pragma unroll
    for (int off = 1; off < 64; off <<= 1) d += __shfl_xor(d, off, 64);
    if (l == 0) Sf[16 * 512 + (t >> 6)] = d;
  }
  __syncthreads();
  if (t == 0) {
    float ssum = 0.0f;
    #pragma unroll
    for (int w2 = 0; w2 < 8; ++w2) ssum += Sf[16 * 512 + w2];
    const int b = pair >> 2, sx = pair & 3;
    atomicAdd(&out[sx * BB + b], ssum * (1.0f / NPTS));
  }
}

extern "C" void kernel_launch(void* const* d_in, const int* in_sizes, int n_in,
                              void* d_out, int out_size, void* d_ws, size_t ws_size,
                              hipStream_t stream) {
  const float* out_pts = (const float*)d_in[0];
  const float* tgt_pts = (const float*)d_in[1];
  float* out = (float*)d_out;

  hipMemsetAsync(out, 0, out_size * sizeof(float), stream);
  if (ws_size >= WS_NEED) {
    __bf16* ws = (__bf16*)d_ws;
    pack2_kernel<<<2 * PAIRS * NPTS / 256, 256, 0, stream>>>(out_pts, tgt_pts, ws);
    chamfer_mfma5_kernel<<<2048, 256, 0, stream>>>(ws, out);
  } else {
    chamfer_pk3_kernel<<<dim3(8, PAIRS, 2), 1024, 0, stream>>>(out_pts, tgt_pts, out);
  }
}